// Round 20
// baseline (394.422 us; speedup 1.0000x reference)
//
#include <hip/hip_runtime.h>
#include <hip/hip_bf16.h>

// GNNEncoder on MI355X. Algebraic reductions:
//  - (ea@eW)@a_e == ea@(eW@a_e): only 3 scalars al_e per edge needed.
//  - loop_attr contribution == mean(incoming al_e) by linearity.
//  - edge LN+dot folded: al = istd*(sum y*(g*v) - mean*G) + C.
// dst-CSR built once; DETERMINISM: atomics only assign arbitrary ranks, csr_sort
// canonicalizes each segment by edge id -> graph-replay == launch_once bitwise.
// MFMA kernels: weights pre-packed into fragment order, tiny per-lane state,
// XOR-swizzled LDS. edge_pre4: transposed GEMMs. xs stored FP8 e4m3 (3.2MB,
// L2-resident), decode folded into attn weight. gat5: edge_b fused.
// Round 20: gat5 grid 1024 -> 2048 blocks (8 blocks/CU = LDS-allowed max;
// was 4/CU). Isolated occupancy test for the latency-bound gather kernel.

typedef short bf16x8 __attribute__((ext_vector_type(8)));
typedef float f32x4 __attribute__((ext_vector_type(4)));
union U8 { uint4 u; bf16x8 v; };

__device__ __forceinline__ unsigned pack2bf(float a, float b) {
  unsigned ua = __float_as_uint(a); ua += 0x7fffu + ((ua >> 16) & 1u);
  unsigned ub = __float_as_uint(b); ub += 0x7fffu + ((ub >> 16) & 1u);
  return (ua >> 16) | (ub & 0xffff0000u);
}
__device__ __forceinline__ unsigned short f2bf(float x) {
  unsigned u = __float_as_uint(x); u += 0x7fffu + ((u >> 16) & 1u);
  return (unsigned short)(u >> 16);
}
__device__ __forceinline__ float bflo(unsigned u) { return __uint_as_float(u << 16); }
__device__ __forceinline__ float bfhi(unsigned u) { return __uint_as_float(u & 0xffff0000u); }

// fp8 e4m3fn encode (RNE on normals, exact denormals, sat at 448)
__device__ __forceinline__ unsigned char f2fp8(float x) {
  unsigned u = __float_as_uint(x);
  unsigned s = (u >> 24) & 0x80u;
  float ax = fabsf(x);
  if (ax >= 448.f) return (unsigned char)(s | 0x7E);
  if (ax < 0.015625f) {
    int m = (int)(ax * 512.f + 0.5f);
    return (unsigned char)(s | (unsigned)m);
  }
  unsigned au = u & 0x7fffffffu;
  au += 0xFFFFFu + ((au >> 20) & 1u);
  unsigned e = (au >> 23) - 120u;
  unsigned m = (au >> 20) & 7u;
  return (unsigned char)(s | (e << 3) | m);
}
// decode to value * 2^-120 (exact)
__device__ __forceinline__ float fp8dec(unsigned b) {
  return __uint_as_float(((b & 0x80u) << 24) | ((b & 0x7fu) << 20));
}

// ---- packall: vprep2 (block 0), wpack (block 1), npack (2..289), gpack (290..337) ----
__global__ __launch_bounds__(256) void packall(
    const float* __restrict__ eW, const float* __restrict__ a_e,
    const float* __restrict__ lng, const float* __restrict__ lnb,
    float* __restrict__ vg,
    const float* __restrict__ eW1, const float* __restrict__ eW2,
    unsigned short* __restrict__ wb,
    const float* __restrict__ nW1, const float* __restrict__ nW2,
    const float* __restrict__ encW, unsigned short* __restrict__ wnb,
    const float* __restrict__ gW, unsigned short* __restrict__ wg) {
  int b = blockIdx.x, t = threadIdx.x;
  if (b == 0) {
    __shared__ float sv[96];
    if (t < 96) {
      int l = t >> 5, i = t & 31;
      const float* w = eW + l * 2048 + i * 64;
      const float* a = a_e + l * 64;
      float s = 0.f;
      for (int c = 0; c < 64; ++c) s += w[c] * a[c];
      sv[t] = s;
      vg[t] = s * lng[i];
    }
    __syncthreads();
    if (t < 3) {
      float G = 0.f, C = 0.f;
      for (int i = 0; i < 32; ++i) {
        float vv = sv[t * 32 + i];
        G += lng[i] * vv;
        C += lnb[i] * vv;
      }
      vg[96 + t] = G;
      vg[99 + t] = C;
    }
  } else if (b == 1) {
    for (int i = t; i < 2048; i += 256) {
      int nt = i >> 9, rem = i & 511, l = rem >> 3, j = rem & 7;
      int k = ((l >> 4) << 3) + j, col = (nt << 4) + (l & 15);
      wb[i] = f2bf(eW1[k * 64 + col]);
    }
    for (int i = t; i < 2048; i += 256) {
      int sn = i >> 9, rem = i & 511, l = rem >> 3, j = rem & 7;
      int s = sn >> 1, nt = sn & 1;
      int k = s * 32 + ((l >> 4) << 3) + j, col = (nt << 4) + (l & 15);
      wb[2048 + i] = f2bf(eW2[k * 32 + col]);
    }
  } else if (b < 290) {
    int i = (b - 2) * 256 + t;  // 0..73727
    if (i < 32768) {
      int fi = i >> 9, rem = i & 511, l = rem >> 3, j = rem & 7;
      int nt = fi >> 2, ks = fi & 3;
      int k = ks * 32 + ((l >> 4) << 3) + j, col = nt * 16 + (l & 15);
      wnb[i] = f2bf(nW1[k * 256 + col]);
    } else if (i < 65536) {
      int i2 = i - 32768;
      int fi = i2 >> 9, rem = i2 & 511, l = rem >> 3, j = rem & 7;
      int nt = fi >> 3, ks = fi & 7;
      int k = ks * 32 + ((l >> 4) << 3) + j, col = nt * 16 + (l & 15);
      wnb[i] = f2bf(nW2[k * 128 + col]);
    } else if (i < 73728) {
      int i3 = i - 65536;
      int fi = i3 >> 9, rem = i3 & 511, l = rem >> 3, j = rem & 7;
      int nt = fi >> 2, ks = fi & 3;
      int k = ks * 32 + ((l >> 4) << 3) + j, col = nt * 16 + (l & 15);
      wnb[i] = f2bf(encW[k * 64 + col]);
    }
  } else {
    int i = (b - 290) * 256 + t;  // 0..12287
    if (i < 12288) {
      int l = i >> 12, rem = i & 4095;
      int fi = rem >> 9, l8 = rem & 511, ln = l8 >> 3, j = l8 & 7;
      int nt = fi >> 1, ks = fi & 1;
      int k = ks * 32 + ((ln >> 4) << 3) + j, col = nt * 16 + (ln & 15);
      wg[i] = f2bf(gW[l * 4096 + k * 64 + col]);
    }
  }
}

// ---- deg + rank in ONE atomic pass (rank order arbitrary; sort canonicalizes) ----
__global__ void deg_rank(const int* __restrict__ dst, int ne,
                         int* __restrict__ deg, int* __restrict__ rank) {
  int i = blockIdx.x * blockDim.x + threadIdx.x;
  int stride = gridDim.x * blockDim.x;
  for (; i < ne; i += stride) rank[i] = atomicAdd(&deg[dst[i]], 1);
}

// ---- scan phase 1: block-local inclusive scan + raw block totals ----
__global__ __launch_bounds__(256) void scan_blk(const int* __restrict__ deg,
                                                int* __restrict__ off,
                                                int* __restrict__ bsum, int n) {
  __shared__ int wsum[4];
  int b = blockIdx.x, t = threadIdx.x;
  int i = b * 256 + t;
  int lane = t & 63, w = t >> 6;
  int v = (i < n) ? deg[i] : 0;
  int s = v;
#pragma unroll
  for (int o = 1; o < 64; o <<= 1) {
    int u = __shfl_up(s, o);
    if (lane >= o) s += u;
  }
  if (lane == 63) wsum[w] = s;
  __syncthreads();
  int add = 0;
#pragma unroll
  for (int ww = 0; ww < 4; ++ww) add += (ww < w) ? wsum[ww] : 0;
  s += add;
  if (i < n) off[i + 1] = s;
  if (t == 255) bsum[b] = s;
}

// ---- scan phase 2: each block computes its own exact int prefix of bsum ----
__global__ __launch_bounds__(256) void scan_add2(const int* __restrict__ bsum,
                                                 int* __restrict__ off, int n) {
  __shared__ int sh[256];
  int b = blockIdx.x, t = threadIdx.x;
  int s = 0;
  for (int j = t; j < b; j += 256) s += bsum[j];
  sh[t] = s;
  __syncthreads();
  for (int o = 128; o > 0; o >>= 1) {
    if (t < o) sh[t] += sh[t + o];
    __syncthreads();
  }
  int add = sh[0];
  int i = b * 256 + t;
  if (i < n) off[i + 1] += add;
  if (i == 0) off[0] = 0;
}

// ---- scatter WITHOUT atomics: position = off[dst] + rank ----
__global__ void scatter_lite(const int* __restrict__ dst, const int* __restrict__ rank,
                             int ne, const int* __restrict__ off, int* __restrict__ eidt) {
  int i = blockIdx.x * blockDim.x + threadIdx.x;
  int stride = gridDim.x * blockDim.x;
  for (; i < ne; i += stride) eidt[off[dst[i]] + rank[i]] = i;
}

// ---- deterministic per-segment sort by edge id; src regathered from srcp[eid] ----
#define SCAP 128
__global__ __launch_bounds__(256) void csr_sort(const int* __restrict__ off,
                                                const int* __restrict__ eidt,
                                                const int* __restrict__ srcp,
                                                int2* __restrict__ csr, int n) {
  __shared__ int seid[16][SCAP];
  int tid = threadIdx.x;
  int qt = tid >> 4, q = tid & 15;
  for (int node = blockIdx.x * 16 + qt; node < n; node += gridDim.x * 16) {
    int s0 = off[node], deg = off[node + 1] - s0;
    if (deg <= SCAP) {
      for (int k = q; k < deg; k += 16) seid[qt][k] = eidt[s0 + k];
      for (int k = q; k < deg; k += 16) {
        int e = seid[qt][k];
        int r = 0;
        for (int m = 0; m < deg; ++m) r += (seid[qt][m] < e) ? 1 : 0;
        csr[s0 + r] = make_int2(srcp[e], e);
      }
    } else {
      for (int k = q; k < deg; k += 16) {
        int e = eidt[s0 + k];
        int r = 0;
        for (int m = 0; m < deg; ++m) r += (eidt[s0 + m] < e) ? 1 : 0;
        csr[s0 + r] = make_int2(srcp[e], e);
      }
    }
  }
}

// ---------------- edge preproc v4: transposed MFMA. block=256 (4 waves), 128 edges ----------------
#define EB 128
__global__ __launch_bounds__(256) void edge_pre4(
    const float* __restrict__ ea, const unsigned short* __restrict__ wb,
    const float* __restrict__ b1, const float* __restrict__ b2,
    const float* __restrict__ vg, float* __restrict__ ale, int ne) {
  __shared__ __align__(16) unsigned short swb[4096];
  __shared__ __align__(16) unsigned short sT[4][32 * 72];
  int tid = threadIdx.x, w = tid >> 6, lane = tid & 63;
  {
    const uint4* g = (const uint4*)wb;
    uint4* s = (uint4*)swb;
    for (int i = tid; i < 512; i += 256) s[i] = g[i];
  }
  __syncthreads();
  int lm = lane & 15, lq = lane >> 4;
  long e0 = (long)blockIdx.x * EB + w * 32;
  bf16x8 eab[2];
#pragma unroll
  for (int eh = 0; eh < 2; ++eh) {
    long e = e0 + eh * 16 + lm;
    if (e >= ne) e = ne - 1;
    const float4* p = (const float4*)(ea + e * 32 + lq * 8);
    float4 u = p[0], v = p[1];
    U8 cc;
    cc.u = make_uint4(pack2bf(u.x, u.y), pack2bf(u.z, u.w), pack2bf(v.x, v.y), pack2bf(v.z, v.w));
    eab[eh] = cc.v;
  }
  f32x4 zero = {0.f, 0.f, 0.f, 0.f};
  f32x4 c1[2][4];
#pragma unroll
  for (int eh = 0; eh < 2; ++eh)
#pragma unroll
    for (int nt = 0; nt < 4; ++nt) c1[eh][nt] = zero;
#pragma unroll
  for (int nt = 0; nt < 4; ++nt) {
    bf16x8 wf = *(const bf16x8*)&swb[nt * 512 + lane * 8];
#pragma unroll
    for (int eh = 0; eh < 2; ++eh)
      c1[eh][nt] = __builtin_amdgcn_mfma_f32_16x16x32_bf16(wf, eab[eh], c1[eh][nt], 0, 0, 0);
  }
#pragma unroll
  for (int nt = 0; nt < 4; ++nt) {
    float4 b1v = *(const float4*)&b1[nt * 16 + lq * 4];
#pragma unroll
    for (int eh = 0; eh < 2; ++eh) {
      int el = eh * 16 + lm;
      unsigned lo = pack2bf(fmaxf(c1[eh][nt][0] + b1v.x, 0.f), fmaxf(c1[eh][nt][1] + b1v.y, 0.f));
      unsigned hi = pack2bf(fmaxf(c1[eh][nt][2] + b1v.z, 0.f), fmaxf(c1[eh][nt][3] + b1v.w, 0.f));
      int blk = nt * 2 + (lq >> 1);
      int addr = el * 72 + (((blk ^ (el & 7)) << 3) | ((lq & 1) << 2));
      *(uint2*)&sT[w][addr] = make_uint2(lo, hi);
    }
  }
  __syncthreads();
  f32x4 c2[2][2];
#pragma unroll
  for (int eh = 0; eh < 2; ++eh)
#pragma unroll
    for (int ih = 0; ih < 2; ++ih) c2[eh][ih] = zero;
#pragma unroll
  for (int eh = 0; eh < 2; ++eh) {
    int el = eh * 16 + lm;
#pragma unroll
    for (int s = 0; s < 2; ++s) {
      int blk = s * 4 + lq;
      bf16x8 tb = *(const bf16x8*)&sT[w][el * 72 + ((blk ^ (el & 7)) << 3)];
#pragma unroll
      for (int ih = 0; ih < 2; ++ih) {
        bf16x8 wf = *(const bf16x8*)&swb[2048 + (s * 2 + ih) * 512 + lane * 8];
        c2[eh][ih] = __builtin_amdgcn_mfma_f32_16x16x32_bf16(wf, tb, c2[eh][ih], 0, 0, 0);
      }
    }
  }
  float4 b2v[2], g0v[2], g1v[2], g2v[2];
#pragma unroll
  for (int ih = 0; ih < 2; ++ih) {
    int ch0 = ih * 16 + lq * 4;
    b2v[ih] = *(const float4*)&b2[ch0];
    g0v[ih] = *(const float4*)&vg[ch0];
    g1v[ih] = *(const float4*)&vg[32 + ch0];
    g2v[ih] = *(const float4*)&vg[64 + ch0];
  }
  float G0 = vg[96], G1 = vg[97], G2 = vg[98];
  float C0 = vg[99], C1 = vg[100], C2 = vg[101];
#pragma unroll
  for (int eh = 0; eh < 2; ++eh) {
    float s = 0.f, q = 0.f, d0 = 0.f, d1 = 0.f, d2 = 0.f;
#pragma unroll
    for (int ih = 0; ih < 2; ++ih) {
      float bb[4] = {b2v[ih].x, b2v[ih].y, b2v[ih].z, b2v[ih].w};
      float g0[4] = {g0v[ih].x, g0v[ih].y, g0v[ih].z, g0v[ih].w};
      float g1[4] = {g1v[ih].x, g1v[ih].y, g1v[ih].z, g1v[ih].w};
      float g2[4] = {g2v[ih].x, g2v[ih].y, g2v[ih].z, g2v[ih].w};
#pragma unroll
      for (int r = 0; r < 4; ++r) {
        float y = c2[eh][ih][r] + bb[r];
        s += y; q += y * y;
        d0 += y * g0[r]; d1 += y * g1[r]; d2 += y * g2[r];
      }
    }
    s += __shfl_xor(s, 16); s += __shfl_xor(s, 32);
    q += __shfl_xor(q, 16); q += __shfl_xor(q, 32);
    d0 += __shfl_xor(d0, 16); d0 += __shfl_xor(d0, 32);
    d1 += __shfl_xor(d1, 16); d1 += __shfl_xor(d1, 32);
    d2 += __shfl_xor(d2, 16); d2 += __shfl_xor(d2, 32);
    long e = e0 + eh * 16 + lm;
    if (lq >= 1 && e < ne) {
      float mean = s * (1.f / 32.f);
      float var = q * (1.f / 32.f) - mean * mean;
      float istd = rsqrtf(var + 1e-5f);
      float d = (lq == 1) ? d0 : (lq == 2) ? d1 : d2;
      float Gp = (lq == 1) ? G0 : (lq == 2) ? G1 : G2;
      float Cp = (lq == 1) ? C0 : (lq == 2) ? C1 : C2;
      ale[(long)(lq - 1) * ne + e] = istd * (d - mean * Gp) + Cp;
    }
  }
}

// ---------------- node preproc v3: MFMA. block=256 (4 waves), 64 nodes ----------------
__global__ __launch_bounds__(256, 2) void node_pre3(
    const float* __restrict__ x, const unsigned short* __restrict__ wnb,
    const float* __restrict__ b1, const float* __restrict__ b2,
    const float* __restrict__ lng, const float* __restrict__ lnb,
    const float* __restrict__ encb, float* __restrict__ z_out,
    float* __restrict__ part, int n) {
  __shared__ __align__(16) unsigned short swb[16384];
  __shared__ __align__(16) unsigned short sT[4][16 * 264];
  __shared__ float sred[4][128];
  int tid = threadIdx.x, w = tid >> 6, lane = tid & 63;
  int lm = lane & 15, lq = lane >> 4;
  long nb = (long)blockIdx.x * 64;
  const uint4* wg = (const uint4*)wnb;
  f32x4 zero = {0.f, 0.f, 0.f, 0.f};

  long row = nb + w * 16 + lm;
  if (row >= n) row = n - 1;
  bf16x8 ax[4];
  const float4* xp = (const float4*)(x + row * 128);
#pragma unroll
  for (int ks = 0; ks < 4; ++ks) {
    float4 u = xp[ks * 8 + lq * 2];
    float4 v = xp[ks * 8 + lq * 2 + 1];
    U8 cc;
    cc.u = make_uint4(pack2bf(u.x, u.y), pack2bf(u.z, u.w), pack2bf(v.x, v.y), pack2bf(v.z, v.w));
    ax[ks] = cc.v;
  }

  for (int h01 = 0; h01 < 2; ++h01) {
    __syncthreads();
    {
      const uint4* src = wg + h01 * 2048;
      uint4* dstv = (uint4*)swb;
      for (int i = tid; i < 2048; i += 256) dstv[i] = src[i];
    }
    __syncthreads();
    f32x4 acc1[8];
#pragma unroll
    for (int nt8 = 0; nt8 < 8; ++nt8) acc1[nt8] = zero;
#pragma unroll
    for (int ks = 0; ks < 4; ++ks)
#pragma unroll
      for (int nt8 = 0; nt8 < 8; ++nt8) {
        bf16x8 bf = *(const bf16x8*)&swb[(nt8 * 4 + ks) * 512 + lane * 8];
        acc1[nt8] = __builtin_amdgcn_mfma_f32_16x16x32_bf16(ax[ks], bf, acc1[nt8], 0, 0, 0);
      }
#pragma unroll
    for (int nt8 = 0; nt8 < 8; ++nt8) {
      int col = (h01 * 8 + nt8) * 16 + lm;
      float bv = b1[col];
#pragma unroll
      for (int r = 0; r < 4; ++r) {
        int rr = lq * 4 + r;
        sT[w][rr * 264 + (col ^ ((rr & 7) << 3))] = f2bf(fmaxf(acc1[nt8][r] + bv, 0.f));
      }
    }
  }

  f32x4 c2[8];
#pragma unroll
  for (int nt = 0; nt < 8; ++nt) c2[nt] = zero;
  for (int ksh = 0; ksh < 2; ++ksh) {
    __syncthreads();
    {
      uint4* dstv = (uint4*)swb;
      for (int i4 = tid; i4 < 2048; i4 += 256) {
        int e = i4 * 8;
        int fc = e >> 9, nt = fc >> 2, ksl = fc & 3;
        int ks = ksh * 4 + ksl;
        long gi = 32768 + (long)(nt * 8 + ks) * 512 + (e & 511);
        dstv[i4] = wg[gi >> 3];
      }
    }
    __syncthreads();
#pragma unroll
    for (int ksl = 0; ksl < 4; ++ksl) {
      int ks = ksh * 4 + ksl;
      bf16x8 at = *(const bf16x8*)&sT[w][lm * 264 + ((ks * 32 + lq * 8) ^ ((lm & 7) << 3))];
#pragma unroll
      for (int nt = 0; nt < 8; ++nt) {
        bf16x8 bf = *(const bf16x8*)&swb[(nt * 4 + ksl) * 512 + lane * 8];
        c2[nt] = __builtin_amdgcn_mfma_f32_16x16x32_bf16(at, bf, c2[nt], 0, 0, 0);
      }
    }
  }

  {
    float yv[8][4], bcol[8], gcol[8], ocol[8];
#pragma unroll
    for (int nt = 0; nt < 8; ++nt) {
      int col = nt * 16 + lm;
      bcol[nt] = b2[col]; gcol[nt] = lng[col]; ocol[nt] = lnb[col];
    }
    float s4[4], q4[4];
#pragma unroll
    for (int r = 0; r < 4; ++r) { s4[r] = 0.f; q4[r] = 0.f; }
#pragma unroll
    for (int nt = 0; nt < 8; ++nt)
#pragma unroll
      for (int r = 0; r < 4; ++r) {
        float y = c2[nt][r] + bcol[nt];
        yv[nt][r] = y;
        s4[r] += y; q4[r] += y * y;
      }
#pragma unroll
    for (int o = 1; o < 16; o <<= 1)
#pragma unroll
      for (int r = 0; r < 4; ++r) {
        s4[r] += __shfl_xor(s4[r], o);
        q4[r] += __shfl_xor(q4[r], o);
      }
#pragma unroll
    for (int r = 0; r < 4; ++r) {
      float mean = s4[r] * (1.f / 128.f);
      float var = q4[r] * (1.f / 128.f) - mean * mean;
      float istd = rsqrtf(var + 1e-5f);
      int rr = lq * 4 + r;
#pragma unroll
      for (int nt = 0; nt < 8; ++nt) {
        float hv = (yv[nt][r] - mean) * istd * gcol[nt] + ocol[nt];
        int col = nt * 16 + lm;
        if (col < 128)
          sT[w][rr * 264 + (col ^ ((rr & 7) << 3))] = f2bf(hv);
      }
    }
  }

  __syncthreads();
  {
    uint4* dstv = (uint4*)swb;
    const uint4* src = wg + (65536 >> 3);
    for (int i = tid; i < 1024; i += 256) dstv[i] = src[i];
  }
  __syncthreads();
  f32x4 c3[4];
#pragma unroll
  for (int nt = 0; nt < 4; ++nt) c3[nt] = zero;
#pragma unroll
  for (int ks = 0; ks < 4; ++ks) {
    bf16x8 at = *(const bf16x8*)&sT[w][lm * 264 + ((ks * 32 + lq * 8) ^ ((lm & 7) << 3))];
#pragma unroll
    for (int nt = 0; nt < 4; ++nt) {
      bf16x8 bf = *(const bf16x8*)&swb[(nt * 4 + ks) * 512 + lane * 8];
      c3[nt] = __builtin_amdgcn_mfma_f32_16x16x32_bf16(at, bf, c3[nt], 0, 0, 0);
    }
  }
  float ps[4], pq[4];
#pragma unroll
  for (int nt = 0; nt < 4; ++nt) { ps[nt] = 0.f; pq[nt] = 0.f; }
#pragma unroll
  for (int nt = 0; nt < 4; ++nt) {
    int col = nt * 16 + lm;
    float eb = encb[col];
#pragma unroll
    for (int r = 0; r < 4; ++r) {
      long nd = nb + w * 16 + lq * 4 + r;
      float z = c3[nt][r] + eb;
      if (nd < n) {
        z_out[nd * 64 + col] = z;
        ps[nt] += z; pq[nt] += z * z;
      }
    }
  }
#pragma unroll
  for (int o = 16; o < 64; o <<= 1)
#pragma unroll
    for (int nt = 0; nt < 4; ++nt) {
      ps[nt] += __shfl_xor(ps[nt], o);
      pq[nt] += __shfl_xor(pq[nt], o);
    }
  if (lq == 0) {
#pragma unroll
    for (int nt = 0; nt < 4; ++nt) {
      sred[w][nt * 16 + lm] = ps[nt];
      sred[w][64 + nt * 16 + lm] = pq[nt];
    }
  }
  __syncthreads();
  if (tid < 128) {
    float t = 0.f;
#pragma unroll
    for (int g = 0; g < 4; ++g) t += sred[g][tid];
    part[(long)blockIdx.x * 128 + tid] = t;
  }
}

// ---- fused MFMA: BN-stats(from part3) + BN-apply(+residual) + xs = h@W + al_s/al_d ----
__global__ __launch_bounds__(256) void xs_bn2(
    const float* __restrict__ z, const float* __restrict__ part3, float invN,
    const float* __restrict__ bng, const float* __restrict__ bnb,
    float* __restrict__ hbuf, int mode,
    const unsigned short* __restrict__ wgat,
    const float* __restrict__ a_s, const float* __restrict__ a_d,
    unsigned char* __restrict__ xsb, float* __restrict__ al_s, float* __restrict__ al_d,
    int n) {
  __shared__ __align__(16) unsigned short swg[4096];
  __shared__ __align__(16) unsigned short shh[4][1024];
  __shared__ float sstat[128];
  int tid = threadIdx.x, w = tid >> 6, lane = tid & 63;
  int lm = lane & 15, lq = lane >> 4;
  {
    const uint4* g = (const uint4*)wgat;
    uint4* s = (uint4*)swg;
    for (int i = tid; i < 512; i += 256) s[i] = g[i];
  }
  if (tid < 128) {  // fold bn_stats: reduce part3 (32 x 128) in-block
    float s = 0.f;
#pragma unroll 4
    for (int g = 0; g < 32; ++g) s += part3[g * 128 + tid];
    sstat[tid] = s;
  }
  __syncthreads();
  float sm, sv;
  {
    float mean = sstat[lane] * invN;
    float var = sstat[64 + lane] * invN - mean * mean;
    sm = mean;
    sv = rsqrtf(var + 1e-5f);
  }
  long nb = (long)blockIdx.x * 64;
  float gg = bng[lane], bb = bnb[lane];
#pragma unroll
  for (int m = 0; m < 16; ++m) {
    long nd = nb + w * 16 + m;
    float hv = 0.f;
    if (nd < n) {
      float t = fmaxf((z[nd * 64 + lane] - sm) * sv * gg + bb, 0.f);
      hv = mode ? hbuf[nd * 64 + lane] + t : t;
      hbuf[nd * 64 + lane] = hv;
    }
    shh[w][m * 64 + (lane ^ ((m & 7) << 3))] = f2bf(hv);
  }
  __syncthreads();
  f32x4 zero = {0.f, 0.f, 0.f, 0.f};
  f32x4 c[4];
#pragma unroll
  for (int nt = 0; nt < 4; ++nt) c[nt] = zero;
#pragma unroll
  for (int ks = 0; ks < 2; ++ks) {
    bf16x8 at = *(const bf16x8*)&shh[w][lm * 64 + ((ks * 32 + lq * 8) ^ ((lm & 7) << 3))];
#pragma unroll
    for (int nt = 0; nt < 4; ++nt) {
      bf16x8 bf = *(const bf16x8*)&swg[(nt * 2 + ks) * 512 + lane * 8];
      c[nt] = __builtin_amdgcn_mfma_f32_16x16x32_bf16(at, bf, c[nt], 0, 0, 0);
    }
  }
  float asv[4], adv[4];
#pragma unroll
  for (int nt = 0; nt < 4; ++nt) { asv[nt] = a_s[nt * 16 + lm]; adv[nt] = a_d[nt * 16 + lm]; }
  float prs[4], prd[4];
#pragma unroll
  for (int r = 0; r < 4; ++r) {
    float s = 0.f, d = 0.f;
#pragma unroll
    for (int nt = 0; nt < 4; ++nt) {
      s += c[nt][r] * asv[nt];
      d += c[nt][r] * adv[nt];
    }
    prs[r] = s; prd[r] = d;
  }
#pragma unroll
  for (int o = 1; o < 16; o <<= 1)
#pragma unroll
    for (int r = 0; r < 4; ++r) {
      prs[r] += __shfl_xor(prs[r], o);
      prd[r] += __shfl_xor(prd[r], o);
    }
#pragma unroll
  for (int nt = 0; nt < 4; ++nt)
#pragma unroll
    for (int r = 0; r < 4; ++r) {
      long nd = nb + w * 16 + lq * 4 + r;
      if (nd < n) xsb[nd * 64 + nt * 16 + lm] = f2fp8(c[nt][r]);
    }
  if (lm == 0) {
#pragma unroll
    for (int r = 0; r < 4; ++r) {
      long nd = nb + w * 16 + lq * 4 + r;
      if (nd < n) { al_s[nd] = prs[r]; al_d[nd] = prd[r]; }
    }
  }
}

// ---------------- GAT v5: direct csr/ale/al_s gathers (edge_b fused), FP8 xs ----------------
#define QCAP 128
__global__ __launch_bounds__(256) void gat5(
    const int* __restrict__ off, const int2* __restrict__ csr,
    const float* __restrict__ ale,
    const float* __restrict__ al_s, const float* __restrict__ al_d,
    const unsigned char* __restrict__ xsb, const float* __restrict__ bias,
    float* __restrict__ gat_out, float* __restrict__ part, int n) {
  __shared__ float2 sal[16][QCAP];
  __shared__ float sred[4][128];
  int tid = threadIdx.x, w = tid >> 6, lane = tid & 63;
  int qt = tid >> 4, q = tid & 15;
  const unsigned* xr = (const unsigned*)xsb;
  float4 bv = *(const float4*)&bias[q * 4];
  float4 psum = make_float4(0.f, 0.f, 0.f, 0.f), psq = psum;
  for (int node = blockIdx.x * 16 + qt; node < n; node += gridDim.x * 16) {
    int s0 = off[node];
    int deg = off[node + 1] - s0;
    bool fits = (deg <= QCAP);
    float aldn = al_d[node];
    float lmax = -3.402823466e38f, lsae = 0.f;
    for (int k = q; k < deg; k += 16) {
      int2 ce = csr[s0 + k];
      float ae = ale[ce.y];
      float b = al_s[ce.x] + ae;
      float a = b + aldn;
      float al = (a >= 0.f) ? a : 0.2f * a;
      lmax = fmaxf(lmax, al);
      lsae += ae;
      if (fits) sal[qt][k] = make_float2(al, __int_as_float(ce.x));
    }
#pragma unroll
    for (int o = 1; o < 16; o <<= 1) {
      lmax = fmaxf(lmax, __shfl_xor(lmax, o));
      lsae += __shfl_xor(lsae, o);
    }
    float ae_self = lsae / fmaxf((float)deg, 1.f);
    float a_self = al_s[node] + aldn + ae_self;
    float al_self = (a_self >= 0.f) ? a_self : 0.2f * a_self;
    float mx = fmaxf(lmax, al_self);
    float lsum = 0.f;
    if (fits) {
      for (int k = q; k < deg; k += 16) {
        float ex = __expf(sal[qt][k].x - mx);
        sal[qt][k].x = ex;
        lsum += ex;
      }
    } else {
      for (int k = q; k < deg; k += 16) {
        int2 ce = csr[s0 + k];
        float b = al_s[ce.x] + ale[ce.y];
        float a = b + aldn;
        float al = (a >= 0.f) ? a : 0.2f * a;
        lsum += __expf(al - mx);
      }
    }
#pragma unroll
    for (int o = 1; o < 16; o <<= 1) lsum += __shfl_xor(lsum, o);
    float exs = __expf(al_self - mx);
    float inv = 1.f / (lsum + exs + 1e-16f);
    unsigned xv = xr[(long)node * 16 + q];
    float es = exs * 0x1p120f;
    float4 acc;
    acc.x = es * fp8dec(xv & 0xFFu);
    acc.y = es * fp8dec((xv >> 8) & 0xFFu);
    acc.z = es * fp8dec((xv >> 16) & 0xFFu);
    acc.w = es * fp8dec(xv >> 24);
    if (fits) {
      int k = 0;
      for (; k + 4 <= deg; k += 4) {
        float2 p0 = sal[qt][k], p1 = sal[qt][k + 1], p2 = sal[qt][k + 2], p3 = sal[qt][k + 3];
        unsigned x0 = xr[(long)__float_as_int(p0.y) * 16 + q];
        unsigned x1 = xr[(long)__float_as_int(p1.y) * 16 + q];
        unsigned x2 = xr[(long)__float_as_int(p2.y) * 16 + q];
        unsigned x3 = xr[(long)__float_as_int(p3.y) * 16 + q];
        float s0s = p0.x * 0x1p120f, s1s = p1.x * 0x1p120f;
        float s2s = p2.x * 0x1p120f, s3s = p3.x * 0x1p120f;
        acc.x += s0s * fp8dec(x0 & 0xFFu) + s1s * fp8dec(x1 & 0xFFu) +
                 s2s * fp8dec(x2 & 0xFFu) + s3s * fp8dec(x3 & 0xFFu);
        acc.y += s0s * fp8dec((x0 >> 8) & 0xFFu) + s1s * fp8dec((x1 >> 8) & 0xFFu) +
                 s2s * fp8dec((x2 >> 8) & 0xFFu) + s3s * fp8dec((x3 >> 8) & 0xFFu);
        acc.z += s0s * fp8dec((x0 >> 16) & 0xFFu) + s1s * fp8dec((x1 >> 16) & 0xFFu) +
                 s2s * fp8dec((x2 >> 16) & 0xFFu) + s3s * fp8dec((x3 >> 16) & 0xFFu);
        acc.w += s0s * fp8dec(x0 >> 24) + s1s * fp8dec(x1 >> 24) +
                 s2s * fp8dec(x2 >> 24) + s3s * fp8dec(x3 >> 24);
      }
      for (; k < deg; ++k) {
        float2 p = sal[qt][k];
        unsigned xk = xr[(long)__float_as_int(p.y) * 16 + q];
        float ss = p.x * 0x1p120f;
        acc.x += ss * fp8dec(xk & 0xFFu);
        acc.y += ss * fp8dec((xk >> 8) & 0xFFu);
        acc.z += ss * fp8dec((xk >> 16) & 0xFFu);
        acc.w += ss * fp8dec(xk >> 24);
      }
    } else {
      for (int k = 0; k < deg; ++k) {
        int2 ce = csr[s0 + k];
        float b = al_s[ce.x] + ale[ce.y];
        float a = b + aldn;
        float al = (a >= 0.f) ? a : 0.2f * a;
        float ss = __expf(al - mx) * 0x1p120f;
        unsigned xk = xr[(long)ce.x * 16 + q];
        acc.x += ss * fp8dec(xk & 0xFFu);
        acc.y += ss * fp8dec((xk >> 8) & 0xFFu);
        acc.z += ss * fp8dec((xk >> 16) & 0xFFu);
        acc.w += ss * fp8dec(xk >> 24);
      }
    }
    acc.x = acc.x * inv + bv.x; acc.y = acc.y * inv + bv.y;
    acc.z = acc.z * inv + bv.z; acc.w = acc.w * inv + bv.w;
    *(float4*)&gat_out[(long)node * 64 + q * 4] = acc;
    psum.x += acc.x; psum.y += acc.y; psum.z += acc.z; psum.w += acc.w;
    psq.x += acc.x * acc.x; psq.y += acc.y * acc.y; psq.z += acc.z * acc.z; psq.w += acc.w * acc.w;
  }
#pragma unroll
  for (int o = 16; o < 64; o <<= 1) {
    psum.x += __shfl_xor(psum.x, o); psum.y += __shfl_xor(psum.y, o);
    psum.z += __shfl_xor(psum.z, o); psum.w += __shfl_xor(psum.w, o);
    psq.x += __shfl_xor(psq.x, o); psq.y += __shfl_xor(psq.y, o);
    psq.z += __shfl_xor(psq.z, o); psq.w += __shfl_xor(psq.w, o);
  }
  if (lane < 16) {
    sred[w][lane * 4 + 0] = psum.x; sred[w][lane * 4 + 1] = psum.y;
    sred[w][lane * 4 + 2] = psum.z; sred[w][lane * 4 + 3] = psum.w;
    sred[w][64 + lane * 4 + 0] = psq.x; sred[w][64 + lane * 4 + 1] = psq.y;
    sred[w][64 + lane * 4 + 2] = psq.z; sred[w][64 + lane * 4 + 3] = psq.w;
  }
  __syncthreads();
  if (tid < 128)
    part[(long)blockIdx.x * 128 + tid] =
        sred[0][tid] + sred[1][tid] + sred[2][tid] + sred[3][tid];
}

// ---------------- BN partial reduce (16 blocks -> 32 x 128) ----------------
__global__ __launch_bounds__(256) void bn_red16(const float* __restrict__ part, int nblk,
                                                float* __restrict__ part3) {
  int t = threadIdx.x, c = t & 127, g2 = t >> 7;
  int row0 = blockIdx.x * 2 + g2;  // 0..31
  float s = 0.f;
  for (int b = row0; b < nblk; b += 32) s += part[(long)b * 128 + c];
  part3[(long)row0 * 128 + c] = s;
}

// ---- fused: BN-stats(from part3) + last BN-apply + residual + mean partials ----
__global__ void gsum_bn(const float* __restrict__ z, const float* __restrict__ part3,
                        float invN, const float* __restrict__ bng,
                        const float* __restrict__ bnb,
                        const float* __restrict__ hprev, int n, float* __restrict__ part) {
  __shared__ float sh[4][64];
  __shared__ float sstat[128];
  int tid = threadIdx.x, w = tid >> 6, lane = tid & 63;
  if (tid < 128) {
    float s = 0.f;
#pragma unroll 4
    for (int g = 0; g < 32; ++g) s += part3[g * 128 + tid];
    sstat[tid] = s;
  }
  __syncthreads();
  float sm, sv;
  {
    float mean = sstat[lane] * invN;
    float var = sstat[64 + lane] * invN - mean * mean;
    sm = mean;
    sv = rsqrtf(var + 1e-5f);
  }
  float gg = bng[lane], bb = bnb[lane];
  int gw = blockIdx.x * 4 + w, nW = gridDim.x * 4;
  float s = 0.f;
  for (int node = gw; node < n; node += nW) {
    float t = fmaxf((z[(long)node * 64 + lane] - sm) * sv * gg + bb, 0.f);
    s += hprev[(long)node * 64 + lane] + t;
  }
  sh[w][lane] = s;
  __syncthreads();
  if (tid < 64)
    part[(long)blockIdx.x * 64 + tid] =
        sh[0][tid] + sh[1][tid] + sh[2][tid] + sh[3][tid];
}

// ---- final: 1024-thr parallel reduce of part2 + LDS out_W MLP ----
__global__ __launch_bounds__(1024) void final2(const float* __restrict__ part, int nblk,
                                               const float* __restrict__ out_W,
                                               const float* __restrict__ out_b,
                                               float* __restrict__ out, float invN) {
  __shared__ float sh[1024];
  __shared__ float gmean[64];
  __shared__ __align__(16) float sW[4096];
  int t = threadIdx.x;
  {
    for (int i = t; i < 1024; i += 1024)
      *(float4*)&sW[i * 4] = *(const float4*)&out_W[i * 4];
  }
  int c = t & 63, gr = t >> 6;
  float s = 0.f;
  for (int b = gr; b < nblk; b += 16) s += part[(long)b * 64 + c];
  sh[t] = s;
  __syncthreads();
  if (t < 64) {
    float tot = 0.f;
#pragma unroll
    for (int q = 0; q < 16; ++q) tot += sh[q * 64 + t];
    gmean[t] = tot * invN;
  }
  __syncthreads();
  if (t < 64) {
    float acc = out_b[t];
#pragma unroll
    for (int k = 0; k < 64; ++k) acc += gmean[k] * sW[k * 64 + t];
    out[t] = fmaxf(acc, 0.f);
  }
}

// ---------------- host launch ----------------
extern "C" void kernel_launch(void* const* d_in, const int* in_sizes, int n_in,
                              void* d_out, int out_size, void* d_ws, size_t ws_size,
                              hipStream_t stream) {
  const float* x        = (const float*)d_in[0];
  const int*   eidx     = (const int*)d_in[1];
  const float* eattr    = (const float*)d_in[2];
  const float* np_W1    = (const float*)d_in[3];
  const float* np_b1    = (const float*)d_in[4];
  const float* np_W2    = (const float*)d_in[5];
  const float* np_b2    = (const float*)d_in[6];
  const float* np_ln_g  = (const float*)d_in[7];
  const float* np_ln_b  = (const float*)d_in[8];
  const float* ep_W1    = (const float*)d_in[9];
  const float* ep_b1    = (const float*)d_in[10];
  const float* ep_W2    = (const float*)d_in[11];
  const float* ep_b2    = (const float*)d_in[12];
  const float* ep_ln_g  = (const float*)d_in[13];
  const float* ep_ln_b  = (const float*)d_in[14];
  const float* enc_W    = (const float*)d_in[15];
  const float* enc_b    = (const float*)d_in[16];
  const float* enc_bn_g = (const float*)d_in[17];
  const float* enc_bn_b = (const float*)d_in[18];
  const float* gat_W    = (const float*)d_in[19];
  const float* gat_eW   = (const float*)d_in[20];
  const float* att_src  = (const float*)d_in[21];
  const float* att_dst  = (const float*)d_in[22];
  const float* att_edge = (const float*)d_in[23];
  const float* gat_b    = (const float*)d_in[24];
  const float* bn_g     = (const float*)d_in[25];
  const float* bn_b     = (const float*)d_in[26];
  const float* out_W    = (const float*)d_in[27];
  const float* out_b    = (const float*)d_in[28];

  const int n = in_sizes[0] / 128;   // 50000
  const int ne = in_sizes[1] / 2;    // 800000
  const int* srcp = eidx;
  const int* dstp = eidx + ne;

  float* f = (float*)d_ws;
  float* hbuf  = f; f += (long)n * 64;
  float* zbuf  = f; f += (long)n * 64;   // also reused as eidt/rank scratch pre-node_pre3
  float* alsb  = f; f += n;
  float* aldb  = f; f += n;
  float* ale   = f; f += 3L * ne;
  float* vgbuf = f; f += 128;
  float* part  = f; f += 262144;      // 2048 x 128
  float* part2 = f; f += 16384;       // 256 x 64
  float* part3 = f; f += 4096;        // 32 x 128
  unsigned short* wbb   = (unsigned short*)f; f += 2048;          // edge weights
  unsigned short* wnb   = (unsigned short*)f; f += 36864;         // node weights
  unsigned short* wgatb = (unsigned short*)f; f += 6144;          // 3 x 4096 gat weights
  unsigned char*  xsb   = (unsigned char*)f;  f += (long)n * 16;  // n*64 fp8
  int* ip = (int*)f;
  int2* csr = (int2*)ip; ip += 2L * ne;
  int* degb = ip; ip += n;
  int* offb = ip; ip += n + 1;
  int* bsum = ip; ip += 256;
  int* eidt = (int*)zbuf;       // ne ints (3.2MB)
  int* rankb = eidt + ne;       // ne ints (3.2MB); zbuf 12.8MB total -- fits

  const int nbEdge = (ne + EB - 1) / EB;     // 6250
  const int nbNode = (n + 63) / 64;          // 782
  const int nbScan = (n + 255) / 256;        // 196
  const float invN = 1.f / n;

  hipMemsetAsync(degb, 0, (size_t)n * sizeof(int), stream);
  packall<<<338, 256, 0, stream>>>(gat_eW, att_edge, ep_ln_g, ep_ln_b, vgbuf,
                                   ep_W1, ep_W2, wbb, np_W1, np_W2, enc_W, wnb,
                                   gat_W, wgatb);
  deg_rank<<<1024, 256, 0, stream>>>(dstp, ne, degb, rankb);
  scan_blk<<<nbScan, 256, 0, stream>>>(degb, offb, bsum, n);
  scan_add2<<<nbScan, 256, 0, stream>>>(bsum, offb, n);
  scatter_lite<<<1024, 256, 0, stream>>>(dstp, rankb, ne, offb, eidt);
  csr_sort<<<1024, 256, 0, stream>>>(offb, eidt, srcp, csr, n);
  edge_pre4<<<nbEdge, 256, 0, stream>>>(eattr, wbb, ep_b1, ep_b2, vgbuf, ale, ne);
  node_pre3<<<nbNode, 256, 0, stream>>>(x, wnb, np_b1, np_b2, np_ln_g, np_ln_b,
                                        enc_b, zbuf, part, n);
  bn_red16<<<16, 256, 0, stream>>>(part, nbNode, part3);
  xs_bn2<<<nbNode, 256, 0, stream>>>(zbuf, part3, invN, enc_bn_g, enc_bn_b, hbuf, 0,
                                     wgatb, att_src, att_dst, xsb, alsb, aldb, n);
  for (int l = 0; l < 3; ++l) {
    gat5<<<2048, 256, 0, stream>>>(offb, csr, ale + (long)l * ne, alsb, aldb,
                                   xsb, gat_b + l * 64, zbuf, part, n);
    bn_red16<<<16, 256, 0, stream>>>(part, 2048, part3);
    if (l < 2) {
      xs_bn2<<<nbNode, 256, 0, stream>>>(zbuf, part3, invN, bn_g + l * 64, bn_b + l * 64,
                                         hbuf, 1, wgatb + (long)(l + 1) * 4096,
                                         att_src + (l + 1) * 64, att_dst + (l + 1) * 64,
                                         xsb, alsb, aldb, n);
    } else {
      gsum_bn<<<256, 256, 0, stream>>>(zbuf, part3, invN, bn_g + l * 64, bn_b + l * 64,
                                       hbuf, n, part2);
    }
  }
  final2<<<1, 1024, 0, stream>>>(part2, 256, out_W, out_b, (float*)d_out, invN);
}

// Round 21
// 368.933 us; speedup vs baseline: 1.0691x; 1.0691x over previous
//
#include <hip/hip_runtime.h>
#include <hip/hip_bf16.h>

// GNNEncoder on MI355X. Algebraic reductions:
//  - (ea@eW)@a_e == ea@(eW@a_e): only 3 scalars al_e per edge needed.
//  - loop_attr contribution == mean(incoming al_e) by linearity.
//  - edge LN+dot folded: al = istd*(sum y*(g*v) - mean*G) + C.
// dst-CSR built once; DETERMINISM: atomics only assign arbitrary ranks, csr_sort
// canonicalizes each segment by edge id -> graph-replay == launch_once bitwise.
// MFMA kernels: weights pre-packed into fragment order, tiny per-lane state,
// XOR-swizzled LDS. edge_pre4: transposed GEMMs. xs stored FP8 e4m3 (3.2MB,
// L2-resident), decode folded into attn weight. gat5: edge_b fused.
// Round 21: revert gat5 grid to 1024 (2048 regressed +25us: L2 gather
// locality beats occupancy; 4 blocks/CU is the local optimum). This is the
// round-17/19 known-good configuration (368.9/369.4 us).

typedef short bf16x8 __attribute__((ext_vector_type(8)));
typedef float f32x4 __attribute__((ext_vector_type(4)));
union U8 { uint4 u; bf16x8 v; };

__device__ __forceinline__ unsigned pack2bf(float a, float b) {
  unsigned ua = __float_as_uint(a); ua += 0x7fffu + ((ua >> 16) & 1u);
  unsigned ub = __float_as_uint(b); ub += 0x7fffu + ((ub >> 16) & 1u);
  return (ua >> 16) | (ub & 0xffff0000u);
}
__device__ __forceinline__ unsigned short f2bf(float x) {
  unsigned u = __float_as_uint(x); u += 0x7fffu + ((u >> 16) & 1u);
  return (unsigned short)(u >> 16);
}
__device__ __forceinline__ float bflo(unsigned u) { return __uint_as_float(u << 16); }
__device__ __forceinline__ float bfhi(unsigned u) { return __uint_as_float(u & 0xffff0000u); }

// fp8 e4m3fn encode (RNE on normals, exact denormals, sat at 448)
__device__ __forceinline__ unsigned char f2fp8(float x) {
  unsigned u = __float_as_uint(x);
  unsigned s = (u >> 24) & 0x80u;
  float ax = fabsf(x);
  if (ax >= 448.f) return (unsigned char)(s | 0x7E);
  if (ax < 0.015625f) {
    int m = (int)(ax * 512.f + 0.5f);
    return (unsigned char)(s | (unsigned)m);
  }
  unsigned au = u & 0x7fffffffu;
  au += 0xFFFFFu + ((au >> 20) & 1u);
  unsigned e = (au >> 23) - 120u;
  unsigned m = (au >> 20) & 7u;
  return (unsigned char)(s | (e << 3) | m);
}
// decode to value * 2^-120 (exact)
__device__ __forceinline__ float fp8dec(unsigned b) {
  return __uint_as_float(((b & 0x80u) << 24) | ((b & 0x7fu) << 20));
}

// ---- packall: vprep2 (block 0), wpack (block 1), npack (2..289), gpack (290..337) ----
__global__ __launch_bounds__(256) void packall(
    const float* __restrict__ eW, const float* __restrict__ a_e,
    const float* __restrict__ lng, const float* __restrict__ lnb,
    float* __restrict__ vg,
    const float* __restrict__ eW1, const float* __restrict__ eW2,
    unsigned short* __restrict__ wb,
    const float* __restrict__ nW1, const float* __restrict__ nW2,
    const float* __restrict__ encW, unsigned short* __restrict__ wnb,
    const float* __restrict__ gW, unsigned short* __restrict__ wg) {
  int b = blockIdx.x, t = threadIdx.x;
  if (b == 0) {
    __shared__ float sv[96];
    if (t < 96) {
      int l = t >> 5, i = t & 31;
      const float* w = eW + l * 2048 + i * 64;
      const float* a = a_e + l * 64;
      float s = 0.f;
      for (int c = 0; c < 64; ++c) s += w[c] * a[c];
      sv[t] = s;
      vg[t] = s * lng[i];
    }
    __syncthreads();
    if (t < 3) {
      float G = 0.f, C = 0.f;
      for (int i = 0; i < 32; ++i) {
        float vv = sv[t * 32 + i];
        G += lng[i] * vv;
        C += lnb[i] * vv;
      }
      vg[96 + t] = G;
      vg[99 + t] = C;
    }
  } else if (b == 1) {
    for (int i = t; i < 2048; i += 256) {
      int nt = i >> 9, rem = i & 511, l = rem >> 3, j = rem & 7;
      int k = ((l >> 4) << 3) + j, col = (nt << 4) + (l & 15);
      wb[i] = f2bf(eW1[k * 64 + col]);
    }
    for (int i = t; i < 2048; i += 256) {
      int sn = i >> 9, rem = i & 511, l = rem >> 3, j = rem & 7;
      int s = sn >> 1, nt = sn & 1;
      int k = s * 32 + ((l >> 4) << 3) + j, col = (nt << 4) + (l & 15);
      wb[2048 + i] = f2bf(eW2[k * 32 + col]);
    }
  } else if (b < 290) {
    int i = (b - 2) * 256 + t;  // 0..73727
    if (i < 32768) {
      int fi = i >> 9, rem = i & 511, l = rem >> 3, j = rem & 7;
      int nt = fi >> 2, ks = fi & 3;
      int k = ks * 32 + ((l >> 4) << 3) + j, col = nt * 16 + (l & 15);
      wnb[i] = f2bf(nW1[k * 256 + col]);
    } else if (i < 65536) {
      int i2 = i - 32768;
      int fi = i2 >> 9, rem = i2 & 511, l = rem >> 3, j = rem & 7;
      int nt = fi >> 3, ks = fi & 7;
      int k = ks * 32 + ((l >> 4) << 3) + j, col = nt * 16 + (l & 15);
      wnb[i] = f2bf(nW2[k * 128 + col]);
    } else if (i < 73728) {
      int i3 = i - 65536;
      int fi = i3 >> 9, rem = i3 & 511, l = rem >> 3, j = rem & 7;
      int nt = fi >> 2, ks = fi & 3;
      int k = ks * 32 + ((l >> 4) << 3) + j, col = nt * 16 + (l & 15);
      wnb[i] = f2bf(encW[k * 64 + col]);
    }
  } else {
    int i = (b - 290) * 256 + t;  // 0..12287
    if (i < 12288) {
      int l = i >> 12, rem = i & 4095;
      int fi = rem >> 9, l8 = rem & 511, ln = l8 >> 3, j = l8 & 7;
      int nt = fi >> 1, ks = fi & 1;
      int k = ks * 32 + ((ln >> 4) << 3) + j, col = nt * 16 + (ln & 15);
      wg[i] = f2bf(gW[l * 4096 + k * 64 + col]);
    }
  }
}

// ---- deg + rank in ONE atomic pass (rank order arbitrary; sort canonicalizes) ----
__global__ void deg_rank(const int* __restrict__ dst, int ne,
                         int* __restrict__ deg, int* __restrict__ rank) {
  int i = blockIdx.x * blockDim.x + threadIdx.x;
  int stride = gridDim.x * blockDim.x;
  for (; i < ne; i += stride) rank[i] = atomicAdd(&deg[dst[i]], 1);
}

// ---- scan phase 1: block-local inclusive scan + raw block totals ----
__global__ __launch_bounds__(256) void scan_blk(const int* __restrict__ deg,
                                                int* __restrict__ off,
                                                int* __restrict__ bsum, int n) {
  __shared__ int wsum[4];
  int b = blockIdx.x, t = threadIdx.x;
  int i = b * 256 + t;
  int lane = t & 63, w = t >> 6;
  int v = (i < n) ? deg[i] : 0;
  int s = v;
#pragma unroll
  for (int o = 1; o < 64; o <<= 1) {
    int u = __shfl_up(s, o);
    if (lane >= o) s += u;
  }
  if (lane == 63) wsum[w] = s;
  __syncthreads();
  int add = 0;
#pragma unroll
  for (int ww = 0; ww < 4; ++ww) add += (ww < w) ? wsum[ww] : 0;
  s += add;
  if (i < n) off[i + 1] = s;
  if (t == 255) bsum[b] = s;
}

// ---- scan phase 2: each block computes its own exact int prefix of bsum ----
__global__ __launch_bounds__(256) void scan_add2(const int* __restrict__ bsum,
                                                 int* __restrict__ off, int n) {
  __shared__ int sh[256];
  int b = blockIdx.x, t = threadIdx.x;
  int s = 0;
  for (int j = t; j < b; j += 256) s += bsum[j];
  sh[t] = s;
  __syncthreads();
  for (int o = 128; o > 0; o >>= 1) {
    if (t < o) sh[t] += sh[t + o];
    __syncthreads();
  }
  int add = sh[0];
  int i = b * 256 + t;
  if (i < n) off[i + 1] += add;
  if (i == 0) off[0] = 0;
}

// ---- scatter WITHOUT atomics: position = off[dst] + rank ----
__global__ void scatter_lite(const int* __restrict__ dst, const int* __restrict__ rank,
                             int ne, const int* __restrict__ off, int* __restrict__ eidt) {
  int i = blockIdx.x * blockDim.x + threadIdx.x;
  int stride = gridDim.x * blockDim.x;
  for (; i < ne; i += stride) eidt[off[dst[i]] + rank[i]] = i;
}

// ---- deterministic per-segment sort by edge id; src regathered from srcp[eid] ----
#define SCAP 128
__global__ __launch_bounds__(256) void csr_sort(const int* __restrict__ off,
                                                const int* __restrict__ eidt,
                                                const int* __restrict__ srcp,
                                                int2* __restrict__ csr, int n) {
  __shared__ int seid[16][SCAP];
  int tid = threadIdx.x;
  int qt = tid >> 4, q = tid & 15;
  for (int node = blockIdx.x * 16 + qt; node < n; node += gridDim.x * 16) {
    int s0 = off[node], deg = off[node + 1] - s0;
    if (deg <= SCAP) {
      for (int k = q; k < deg; k += 16) seid[qt][k] = eidt[s0 + k];
      for (int k = q; k < deg; k += 16) {
        int e = seid[qt][k];
        int r = 0;
        for (int m = 0; m < deg; ++m) r += (seid[qt][m] < e) ? 1 : 0;
        csr[s0 + r] = make_int2(srcp[e], e);
      }
    } else {
      for (int k = q; k < deg; k += 16) {
        int e = eidt[s0 + k];
        int r = 0;
        for (int m = 0; m < deg; ++m) r += (eidt[s0 + m] < e) ? 1 : 0;
        csr[s0 + r] = make_int2(srcp[e], e);
      }
    }
  }
}

// ---------------- edge preproc v4: transposed MFMA. block=256 (4 waves), 128 edges ----------------
#define EB 128
__global__ __launch_bounds__(256) void edge_pre4(
    const float* __restrict__ ea, const unsigned short* __restrict__ wb,
    const float* __restrict__ b1, const float* __restrict__ b2,
    const float* __restrict__ vg, float* __restrict__ ale, int ne) {
  __shared__ __align__(16) unsigned short swb[4096];
  __shared__ __align__(16) unsigned short sT[4][32 * 72];
  int tid = threadIdx.x, w = tid >> 6, lane = tid & 63;
  {
    const uint4* g = (const uint4*)wb;
    uint4* s = (uint4*)swb;
    for (int i = tid; i < 512; i += 256) s[i] = g[i];
  }
  __syncthreads();
  int lm = lane & 15, lq = lane >> 4;
  long e0 = (long)blockIdx.x * EB + w * 32;
  bf16x8 eab[2];
#pragma unroll
  for (int eh = 0; eh < 2; ++eh) {
    long e = e0 + eh * 16 + lm;
    if (e >= ne) e = ne - 1;
    const float4* p = (const float4*)(ea + e * 32 + lq * 8);
    float4 u = p[0], v = p[1];
    U8 cc;
    cc.u = make_uint4(pack2bf(u.x, u.y), pack2bf(u.z, u.w), pack2bf(v.x, v.y), pack2bf(v.z, v.w));
    eab[eh] = cc.v;
  }
  f32x4 zero = {0.f, 0.f, 0.f, 0.f};
  f32x4 c1[2][4];
#pragma unroll
  for (int eh = 0; eh < 2; ++eh)
#pragma unroll
    for (int nt = 0; nt < 4; ++nt) c1[eh][nt] = zero;
#pragma unroll
  for (int nt = 0; nt < 4; ++nt) {
    bf16x8 wf = *(const bf16x8*)&swb[nt * 512 + lane * 8];
#pragma unroll
    for (int eh = 0; eh < 2; ++eh)
      c1[eh][nt] = __builtin_amdgcn_mfma_f32_16x16x32_bf16(wf, eab[eh], c1[eh][nt], 0, 0, 0);
  }
#pragma unroll
  for (int nt = 0; nt < 4; ++nt) {
    float4 b1v = *(const float4*)&b1[nt * 16 + lq * 4];
#pragma unroll
    for (int eh = 0; eh < 2; ++eh) {
      int el = eh * 16 + lm;
      unsigned lo = pack2bf(fmaxf(c1[eh][nt][0] + b1v.x, 0.f), fmaxf(c1[eh][nt][1] + b1v.y, 0.f));
      unsigned hi = pack2bf(fmaxf(c1[eh][nt][2] + b1v.z, 0.f), fmaxf(c1[eh][nt][3] + b1v.w, 0.f));
      int blk = nt * 2 + (lq >> 1);
      int addr = el * 72 + (((blk ^ (el & 7)) << 3) | ((lq & 1) << 2));
      *(uint2*)&sT[w][addr] = make_uint2(lo, hi);
    }
  }
  __syncthreads();
  f32x4 c2[2][2];
#pragma unroll
  for (int eh = 0; eh < 2; ++eh)
#pragma unroll
    for (int ih = 0; ih < 2; ++ih) c2[eh][ih] = zero;
#pragma unroll
  for (int eh = 0; eh < 2; ++eh) {
    int el = eh * 16 + lm;
#pragma unroll
    for (int s = 0; s < 2; ++s) {
      int blk = s * 4 + lq;
      bf16x8 tb = *(const bf16x8*)&sT[w][el * 72 + ((blk ^ (el & 7)) << 3)];
#pragma unroll
      for (int ih = 0; ih < 2; ++ih) {
        bf16x8 wf = *(const bf16x8*)&swb[2048 + (s * 2 + ih) * 512 + lane * 8];
        c2[eh][ih] = __builtin_amdgcn_mfma_f32_16x16x32_bf16(wf, tb, c2[eh][ih], 0, 0, 0);
      }
    }
  }
  float4 b2v[2], g0v[2], g1v[2], g2v[2];
#pragma unroll
  for (int ih = 0; ih < 2; ++ih) {
    int ch0 = ih * 16 + lq * 4;
    b2v[ih] = *(const float4*)&b2[ch0];
    g0v[ih] = *(const float4*)&vg[ch0];
    g1v[ih] = *(const float4*)&vg[32 + ch0];
    g2v[ih] = *(const float4*)&vg[64 + ch0];
  }
  float G0 = vg[96], G1 = vg[97], G2 = vg[98];
  float C0 = vg[99], C1 = vg[100], C2 = vg[101];
#pragma unroll
  for (int eh = 0; eh < 2; ++eh) {
    float s = 0.f, q = 0.f, d0 = 0.f, d1 = 0.f, d2 = 0.f;
#pragma unroll
    for (int ih = 0; ih < 2; ++ih) {
      float bb[4] = {b2v[ih].x, b2v[ih].y, b2v[ih].z, b2v[ih].w};
      float g0[4] = {g0v[ih].x, g0v[ih].y, g0v[ih].z, g0v[ih].w};
      float g1[4] = {g1v[ih].x, g1v[ih].y, g1v[ih].z, g1v[ih].w};
      float g2[4] = {g2v[ih].x, g2v[ih].y, g2v[ih].z, g2v[ih].w};
#pragma unroll
      for (int r = 0; r < 4; ++r) {
        float y = c2[eh][ih][r] + bb[r];
        s += y; q += y * y;
        d0 += y * g0[r]; d1 += y * g1[r]; d2 += y * g2[r];
      }
    }
    s += __shfl_xor(s, 16); s += __shfl_xor(s, 32);
    q += __shfl_xor(q, 16); q += __shfl_xor(q, 32);
    d0 += __shfl_xor(d0, 16); d0 += __shfl_xor(d0, 32);
    d1 += __shfl_xor(d1, 16); d1 += __shfl_xor(d1, 32);
    d2 += __shfl_xor(d2, 16); d2 += __shfl_xor(d2, 32);
    long e = e0 + eh * 16 + lm;
    if (lq >= 1 && e < ne) {
      float mean = s * (1.f / 32.f);
      float var = q * (1.f / 32.f) - mean * mean;
      float istd = rsqrtf(var + 1e-5f);
      float d = (lq == 1) ? d0 : (lq == 2) ? d1 : d2;
      float Gp = (lq == 1) ? G0 : (lq == 2) ? G1 : G2;
      float Cp = (lq == 1) ? C0 : (lq == 2) ? C1 : C2;
      ale[(long)(lq - 1) * ne + e] = istd * (d - mean * Gp) + Cp;
    }
  }
}

// ---------------- node preproc v3: MFMA. block=256 (4 waves), 64 nodes ----------------
__global__ __launch_bounds__(256, 2) void node_pre3(
    const float* __restrict__ x, const unsigned short* __restrict__ wnb,
    const float* __restrict__ b1, const float* __restrict__ b2,
    const float* __restrict__ lng, const float* __restrict__ lnb,
    const float* __restrict__ encb, float* __restrict__ z_out,
    float* __restrict__ part, int n) {
  __shared__ __align__(16) unsigned short swb[16384];
  __shared__ __align__(16) unsigned short sT[4][16 * 264];
  __shared__ float sred[4][128];
  int tid = threadIdx.x, w = tid >> 6, lane = tid & 63;
  int lm = lane & 15, lq = lane >> 4;
  long nb = (long)blockIdx.x * 64;
  const uint4* wg = (const uint4*)wnb;
  f32x4 zero = {0.f, 0.f, 0.f, 0.f};

  long row = nb + w * 16 + lm;
  if (row >= n) row = n - 1;
  bf16x8 ax[4];
  const float4* xp = (const float4*)(x + row * 128);
#pragma unroll
  for (int ks = 0; ks < 4; ++ks) {
    float4 u = xp[ks * 8 + lq * 2];
    float4 v = xp[ks * 8 + lq * 2 + 1];
    U8 cc;
    cc.u = make_uint4(pack2bf(u.x, u.y), pack2bf(u.z, u.w), pack2bf(v.x, v.y), pack2bf(v.z, v.w));
    ax[ks] = cc.v;
  }

  for (int h01 = 0; h01 < 2; ++h01) {
    __syncthreads();
    {
      const uint4* src = wg + h01 * 2048;
      uint4* dstv = (uint4*)swb;
      for (int i = tid; i < 2048; i += 256) dstv[i] = src[i];
    }
    __syncthreads();
    f32x4 acc1[8];
#pragma unroll
    for (int nt8 = 0; nt8 < 8; ++nt8) acc1[nt8] = zero;
#pragma unroll
    for (int ks = 0; ks < 4; ++ks)
#pragma unroll
      for (int nt8 = 0; nt8 < 8; ++nt8) {
        bf16x8 bf = *(const bf16x8*)&swb[(nt8 * 4 + ks) * 512 + lane * 8];
        acc1[nt8] = __builtin_amdgcn_mfma_f32_16x16x32_bf16(ax[ks], bf, acc1[nt8], 0, 0, 0);
      }
#pragma unroll
    for (int nt8 = 0; nt8 < 8; ++nt8) {
      int col = (h01 * 8 + nt8) * 16 + lm;
      float bv = b1[col];
#pragma unroll
      for (int r = 0; r < 4; ++r) {
        int rr = lq * 4 + r;
        sT[w][rr * 264 + (col ^ ((rr & 7) << 3))] = f2bf(fmaxf(acc1[nt8][r] + bv, 0.f));
      }
    }
  }

  f32x4 c2[8];
#pragma unroll
  for (int nt = 0; nt < 8; ++nt) c2[nt] = zero;
  for (int ksh = 0; ksh < 2; ++ksh) {
    __syncthreads();
    {
      uint4* dstv = (uint4*)swb;
      for (int i4 = tid; i4 < 2048; i4 += 256) {
        int e = i4 * 8;
        int fc = e >> 9, nt = fc >> 2, ksl = fc & 3;
        int ks = ksh * 4 + ksl;
        long gi = 32768 + (long)(nt * 8 + ks) * 512 + (e & 511);
        dstv[i4] = wg[gi >> 3];
      }
    }
    __syncthreads();
#pragma unroll
    for (int ksl = 0; ksl < 4; ++ksl) {
      int ks = ksh * 4 + ksl;
      bf16x8 at = *(const bf16x8*)&sT[w][lm * 264 + ((ks * 32 + lq * 8) ^ ((lm & 7) << 3))];
#pragma unroll
      for (int nt = 0; nt < 8; ++nt) {
        bf16x8 bf = *(const bf16x8*)&swb[(nt * 4 + ksl) * 512 + lane * 8];
        c2[nt] = __builtin_amdgcn_mfma_f32_16x16x32_bf16(at, bf, c2[nt], 0, 0, 0);
      }
    }
  }

  {
    float yv[8][4], bcol[8], gcol[8], ocol[8];
#pragma unroll
    for (int nt = 0; nt < 8; ++nt) {
      int col = nt * 16 + lm;
      bcol[nt] = b2[col]; gcol[nt] = lng[col]; ocol[nt] = lnb[col];
    }
    float s4[4], q4[4];
#pragma unroll
    for (int r = 0; r < 4; ++r) { s4[r] = 0.f; q4[r] = 0.f; }
#pragma unroll
    for (int nt = 0; nt < 8; ++nt)
#pragma unroll
      for (int r = 0; r < 4; ++r) {
        float y = c2[nt][r] + bcol[nt];
        yv[nt][r] = y;
        s4[r] += y; q4[r] += y * y;
      }
#pragma unroll
    for (int o = 1; o < 16; o <<= 1)
#pragma unroll
      for (int r = 0; r < 4; ++r) {
        s4[r] += __shfl_xor(s4[r], o);
        q4[r] += __shfl_xor(q4[r], o);
      }
#pragma unroll
    for (int r = 0; r < 4; ++r) {
      float mean = s4[r] * (1.f / 128.f);
      float var = q4[r] * (1.f / 128.f) - mean * mean;
      float istd = rsqrtf(var + 1e-5f);
      int rr = lq * 4 + r;
#pragma unroll
      for (int nt = 0; nt < 8; ++nt) {
        float hv = (yv[nt][r] - mean) * istd * gcol[nt] + ocol[nt];
        int col = nt * 16 + lm;
        if (col < 128)
          sT[w][rr * 264 + (col ^ ((rr & 7) << 3))] = f2bf(hv);
      }
    }
  }

  __syncthreads();
  {
    uint4* dstv = (uint4*)swb;
    const uint4* src = wg + (65536 >> 3);
    for (int i = tid; i < 1024; i += 256) dstv[i] = src[i];
  }
  __syncthreads();
  f32x4 c3[4];
#pragma unroll
  for (int nt = 0; nt < 4; ++nt) c3[nt] = zero;
#pragma unroll
  for (int ks = 0; ks < 4; ++ks) {
    bf16x8 at = *(const bf16x8*)&sT[w][lm * 264 + ((ks * 32 + lq * 8) ^ ((lm & 7) << 3))];
#pragma unroll
    for (int nt = 0; nt < 4; ++nt) {
      bf16x8 bf = *(const bf16x8*)&swb[(nt * 4 + ks) * 512 + lane * 8];
      c3[nt] = __builtin_amdgcn_mfma_f32_16x16x32_bf16(at, bf, c3[nt], 0, 0, 0);
    }
  }
  float ps[4], pq[4];
#pragma unroll
  for (int nt = 0; nt < 4; ++nt) { ps[nt] = 0.f; pq[nt] = 0.f; }
#pragma unroll
  for (int nt = 0; nt < 4; ++nt) {
    int col = nt * 16 + lm;
    float eb = encb[col];
#pragma unroll
    for (int r = 0; r < 4; ++r) {
      long nd = nb + w * 16 + lq * 4 + r;
      float z = c3[nt][r] + eb;
      if (nd < n) {
        z_out[nd * 64 + col] = z;
        ps[nt] += z; pq[nt] += z * z;
      }
    }
  }
#pragma unroll
  for (int o = 16; o < 64; o <<= 1)
#pragma unroll
    for (int nt = 0; nt < 4; ++nt) {
      ps[nt] += __shfl_xor(ps[nt], o);
      pq[nt] += __shfl_xor(pq[nt], o);
    }
  if (lq == 0) {
#pragma unroll
    for (int nt = 0; nt < 4; ++nt) {
      sred[w][nt * 16 + lm] = ps[nt];
      sred[w][64 + nt * 16 + lm] = pq[nt];
    }
  }
  __syncthreads();
  if (tid < 128) {
    float t = 0.f;
#pragma unroll
    for (int g = 0; g < 4; ++g) t += sred[g][tid];
    part[(long)blockIdx.x * 128 + tid] = t;
  }
}

// ---- fused MFMA: BN-stats(from part3) + BN-apply(+residual) + xs = h@W + al_s/al_d ----
__global__ __launch_bounds__(256) void xs_bn2(
    const float* __restrict__ z, const float* __restrict__ part3, float invN,
    const float* __restrict__ bng, const float* __restrict__ bnb,
    float* __restrict__ hbuf, int mode,
    const unsigned short* __restrict__ wgat,
    const float* __restrict__ a_s, const float* __restrict__ a_d,
    unsigned char* __restrict__ xsb, float* __restrict__ al_s, float* __restrict__ al_d,
    int n) {
  __shared__ __align__(16) unsigned short swg[4096];
  __shared__ __align__(16) unsigned short shh[4][1024];
  __shared__ float sstat[128];
  int tid = threadIdx.x, w = tid >> 6, lane = tid & 63;
  int lm = lane & 15, lq = lane >> 4;
  {
    const uint4* g = (const uint4*)wgat;
    uint4* s = (uint4*)swg;
    for (int i = tid; i < 512; i += 256) s[i] = g[i];
  }
  if (tid < 128) {  // fold bn_stats: reduce part3 (32 x 128) in-block
    float s = 0.f;
#pragma unroll 4
    for (int g = 0; g < 32; ++g) s += part3[g * 128 + tid];
    sstat[tid] = s;
  }
  __syncthreads();
  float sm, sv;
  {
    float mean = sstat[lane] * invN;
    float var = sstat[64 + lane] * invN - mean * mean;
    sm = mean;
    sv = rsqrtf(var + 1e-5f);
  }
  long nb = (long)blockIdx.x * 64;
  float gg = bng[lane], bb = bnb[lane];
#pragma unroll
  for (int m = 0; m < 16; ++m) {
    long nd = nb + w * 16 + m;
    float hv = 0.f;
    if (nd < n) {
      float t = fmaxf((z[nd * 64 + lane] - sm) * sv * gg + bb, 0.f);
      hv = mode ? hbuf[nd * 64 + lane] + t : t;
      hbuf[nd * 64 + lane] = hv;
    }
    shh[w][m * 64 + (lane ^ ((m & 7) << 3))] = f2bf(hv);
  }
  __syncthreads();
  f32x4 zero = {0.f, 0.f, 0.f, 0.f};
  f32x4 c[4];
#pragma unroll
  for (int nt = 0; nt < 4; ++nt) c[nt] = zero;
#pragma unroll
  for (int ks = 0; ks < 2; ++ks) {
    bf16x8 at = *(const bf16x8*)&shh[w][lm * 64 + ((ks * 32 + lq * 8) ^ ((lm & 7) << 3))];
#pragma unroll
    for (int nt = 0; nt < 4; ++nt) {
      bf16x8 bf = *(const bf16x8*)&swg[(nt * 2 + ks) * 512 + lane * 8];
      c[nt] = __builtin_amdgcn_mfma_f32_16x16x32_bf16(at, bf, c[nt], 0, 0, 0);
    }
  }
  float asv[4], adv[4];
#pragma unroll
  for (int nt = 0; nt < 4; ++nt) { asv[nt] = a_s[nt * 16 + lm]; adv[nt] = a_d[nt * 16 + lm]; }
  float prs[4], prd[4];
#pragma unroll
  for (int r = 0; r < 4; ++r) {
    float s = 0.f, d = 0.f;
#pragma unroll
    for (int nt = 0; nt < 4; ++nt) {
      s += c[nt][r] * asv[nt];
      d += c[nt][r] * adv[nt];
    }
    prs[r] = s; prd[r] = d;
  }
#pragma unroll
  for (int o = 1; o < 16; o <<= 1)
#pragma unroll
    for (int r = 0; r < 4; ++r) {
      prs[r] += __shfl_xor(prs[r], o);
      prd[r] += __shfl_xor(prd[r], o);
    }
#pragma unroll
  for (int nt = 0; nt < 4; ++nt)
#pragma unroll
    for (int r = 0; r < 4; ++r) {
      long nd = nb + w * 16 + lq * 4 + r;
      if (nd < n) xsb[nd * 64 + nt * 16 + lm] = f2fp8(c[nt][r]);
    }
  if (lm == 0) {
#pragma unroll
    for (int r = 0; r < 4; ++r) {
      long nd = nb + w * 16 + lq * 4 + r;
      if (nd < n) { al_s[nd] = prs[r]; al_d[nd] = prd[r]; }
    }
  }
}

// ---------------- GAT v5: direct csr/ale/al_s gathers (edge_b fused), FP8 xs ----------------
#define QCAP 128
__global__ __launch_bounds__(256) void gat5(
    const int* __restrict__ off, const int2* __restrict__ csr,
    const float* __restrict__ ale,
    const float* __restrict__ al_s, const float* __restrict__ al_d,
    const unsigned char* __restrict__ xsb, const float* __restrict__ bias,
    float* __restrict__ gat_out, float* __restrict__ part, int n) {
  __shared__ float2 sal[16][QCAP];
  __shared__ float sred[4][128];
  int tid = threadIdx.x, w = tid >> 6, lane = tid & 63;
  int qt = tid >> 4, q = tid & 15;
  const unsigned* xr = (const unsigned*)xsb;
  float4 bv = *(const float4*)&bias[q * 4];
  float4 psum = make_float4(0.f, 0.f, 0.f, 0.f), psq = psum;
  for (int node = blockIdx.x * 16 + qt; node < n; node += gridDim.x * 16) {
    int s0 = off[node];
    int deg = off[node + 1] - s0;
    bool fits = (deg <= QCAP);
    float aldn = al_d[node];
    float lmax = -3.402823466e38f, lsae = 0.f;
    for (int k = q; k < deg; k += 16) {
      int2 ce = csr[s0 + k];
      float ae = ale[ce.y];
      float b = al_s[ce.x] + ae;
      float a = b + aldn;
      float al = (a >= 0.f) ? a : 0.2f * a;
      lmax = fmaxf(lmax, al);
      lsae += ae;
      if (fits) sal[qt][k] = make_float2(al, __int_as_float(ce.x));
    }
#pragma unroll
    for (int o = 1; o < 16; o <<= 1) {
      lmax = fmaxf(lmax, __shfl_xor(lmax, o));
      lsae += __shfl_xor(lsae, o);
    }
    float ae_self = lsae / fmaxf((float)deg, 1.f);
    float a_self = al_s[node] + aldn + ae_self;
    float al_self = (a_self >= 0.f) ? a_self : 0.2f * a_self;
    float mx = fmaxf(lmax, al_self);
    float lsum = 0.f;
    if (fits) {
      for (int k = q; k < deg; k += 16) {
        float ex = __expf(sal[qt][k].x - mx);
        sal[qt][k].x = ex;
        lsum += ex;
      }
    } else {
      for (int k = q; k < deg; k += 16) {
        int2 ce = csr[s0 + k];
        float b = al_s[ce.x] + ale[ce.y];
        float a = b + aldn;
        float al = (a >= 0.f) ? a : 0.2f * a;
        lsum += __expf(al - mx);
      }
    }
#pragma unroll
    for (int o = 1; o < 16; o <<= 1) lsum += __shfl_xor(lsum, o);
    float exs = __expf(al_self - mx);
    float inv = 1.f / (lsum + exs + 1e-16f);
    unsigned xv = xr[(long)node * 16 + q];
    float es = exs * 0x1p120f;
    float4 acc;
    acc.x = es * fp8dec(xv & 0xFFu);
    acc.y = es * fp8dec((xv >> 8) & 0xFFu);
    acc.z = es * fp8dec((xv >> 16) & 0xFFu);
    acc.w = es * fp8dec(xv >> 24);
    if (fits) {
      int k = 0;
      for (; k + 4 <= deg; k += 4) {
        float2 p0 = sal[qt][k], p1 = sal[qt][k + 1], p2 = sal[qt][k + 2], p3 = sal[qt][k + 3];
        unsigned x0 = xr[(long)__float_as_int(p0.y) * 16 + q];
        unsigned x1 = xr[(long)__float_as_int(p1.y) * 16 + q];
        unsigned x2 = xr[(long)__float_as_int(p2.y) * 16 + q];
        unsigned x3 = xr[(long)__float_as_int(p3.y) * 16 + q];
        float s0s = p0.x * 0x1p120f, s1s = p1.x * 0x1p120f;
        float s2s = p2.x * 0x1p120f, s3s = p3.x * 0x1p120f;
        acc.x += s0s * fp8dec(x0 & 0xFFu) + s1s * fp8dec(x1 & 0xFFu) +
                 s2s * fp8dec(x2 & 0xFFu) + s3s * fp8dec(x3 & 0xFFu);
        acc.y += s0s * fp8dec((x0 >> 8) & 0xFFu) + s1s * fp8dec((x1 >> 8) & 0xFFu) +
                 s2s * fp8dec((x2 >> 8) & 0xFFu) + s3s * fp8dec((x3 >> 8) & 0xFFu);
        acc.z += s0s * fp8dec((x0 >> 16) & 0xFFu) + s1s * fp8dec((x1 >> 16) & 0xFFu) +
                 s2s * fp8dec((x2 >> 16) & 0xFFu) + s3s * fp8dec((x3 >> 16) & 0xFFu);
        acc.w += s0s * fp8dec(x0 >> 24) + s1s * fp8dec(x1 >> 24) +
                 s2s * fp8dec(x2 >> 24) + s3s * fp8dec(x3 >> 24);
      }
      for (; k < deg; ++k) {
        float2 p = sal[qt][k];
        unsigned xk = xr[(long)__float_as_int(p.y) * 16 + q];
        float ss = p.x * 0x1p120f;
        acc.x += ss * fp8dec(xk & 0xFFu);
        acc.y += ss * fp8dec((xk >> 8) & 0xFFu);
        acc.z += ss * fp8dec((xk >> 16) & 0xFFu);
        acc.w += ss * fp8dec(xk >> 24);
      }
    } else {
      for (int k = 0; k < deg; ++k) {
        int2 ce = csr[s0 + k];
        float b = al_s[ce.x] + ale[ce.y];
        float a = b + aldn;
        float al = (a >= 0.f) ? a : 0.2f * a;
        float ss = __expf(al - mx) * 0x1p120f;
        unsigned xk = xr[(long)ce.x * 16 + q];
        acc.x += ss * fp8dec(xk & 0xFFu);
        acc.y += ss * fp8dec((xk >> 8) & 0xFFu);
        acc.z += ss * fp8dec((xk >> 16) & 0xFFu);
        acc.w += ss * fp8dec(xk >> 24);
      }
    }
    acc.x = acc.x * inv + bv.x; acc.y = acc.y * inv + bv.y;
    acc.z = acc.z * inv + bv.z; acc.w = acc.w * inv + bv.w;
    *(float4*)&gat_out[(long)node * 64 + q * 4] = acc;
    psum.x += acc.x; psum.y += acc.y; psum.z += acc.z; psum.w += acc.w;
    psq.x += acc.x * acc.x; psq.y += acc.y * acc.y; psq.z += acc.z * acc.z; psq.w += acc.w * acc.w;
  }
#pragma unroll
  for (int o = 16; o < 64; o <<= 1) {
    psum.x += __shfl_xor(psum.x, o); psum.y += __shfl_xor(psum.y, o);
    psum.z += __shfl_xor(psum.z, o); psum.w += __shfl_xor(psum.w, o);
    psq.x += __shfl_xor(psq.x, o); psq.y += __shfl_xor(psq.y, o);
    psq.z += __shfl_xor(psq.z, o); psq.w += __shfl_xor(psq.w, o);
  }
  if (lane < 16) {
    sred[w][lane * 4 + 0] = psum.x; sred[w][lane * 4 + 1] = psum.y;
    sred[w][lane * 4 + 2] = psum.z; sred[w][lane * 4 + 3] = psum.w;
    sred[w][64 + lane * 4 + 0] = psq.x; sred[w][64 + lane * 4 + 1] = psq.y;
    sred[w][64 + lane * 4 + 2] = psq.z; sred[w][64 + lane * 4 + 3] = psq.w;
  }
  __syncthreads();
  if (tid < 128)
    part[(long)blockIdx.x * 128 + tid] =
        sred[0][tid] + sred[1][tid] + sred[2][tid] + sred[3][tid];
}

// ---------------- BN partial reduce (16 blocks -> 32 x 128) ----------------
__global__ __launch_bounds__(256) void bn_red16(const float* __restrict__ part, int nblk,
                                                float* __restrict__ part3) {
  int t = threadIdx.x, c = t & 127, g2 = t >> 7;
  int row0 = blockIdx.x * 2 + g2;  // 0..31
  float s = 0.f;
  for (int b = row0; b < nblk; b += 32) s += part[(long)b * 128 + c];
  part3[(long)row0 * 128 + c] = s;
}

// ---- fused: BN-stats(from part3) + last BN-apply + residual + mean partials ----
__global__ void gsum_bn(const float* __restrict__ z, const float* __restrict__ part3,
                        float invN, const float* __restrict__ bng,
                        const float* __restrict__ bnb,
                        const float* __restrict__ hprev, int n, float* __restrict__ part) {
  __shared__ float sh[4][64];
  __shared__ float sstat[128];
  int tid = threadIdx.x, w = tid >> 6, lane = tid & 63;
  if (tid < 128) {
    float s = 0.f;
#pragma unroll 4
    for (int g = 0; g < 32; ++g) s += part3[g * 128 + tid];
    sstat[tid] = s;
  }
  __syncthreads();
  float sm, sv;
  {
    float mean = sstat[lane] * invN;
    float var = sstat[64 + lane] * invN - mean * mean;
    sm = mean;
    sv = rsqrtf(var + 1e-5f);
  }
  float gg = bng[lane], bb = bnb[lane];
  int gw = blockIdx.x * 4 + w, nW = gridDim.x * 4;
  float s = 0.f;
  for (int node = gw; node < n; node += nW) {
    float t = fmaxf((z[(long)node * 64 + lane] - sm) * sv * gg + bb, 0.f);
    s += hprev[(long)node * 64 + lane] + t;
  }
  sh[w][lane] = s;
  __syncthreads();
  if (tid < 64)
    part[(long)blockIdx.x * 64 + tid] =
        sh[0][tid] + sh[1][tid] + sh[2][tid] + sh[3][tid];
}

// ---- final: 1024-thr parallel reduce of part2 + LDS out_W MLP ----
__global__ __launch_bounds__(1024) void final2(const float* __restrict__ part, int nblk,
                                               const float* __restrict__ out_W,
                                               const float* __restrict__ out_b,
                                               float* __restrict__ out, float invN) {
  __shared__ float sh[1024];
  __shared__ float gmean[64];
  __shared__ __align__(16) float sW[4096];
  int t = threadIdx.x;
  {
    for (int i = t; i < 1024; i += 1024)
      *(float4*)&sW[i * 4] = *(const float4*)&out_W[i * 4];
  }
  int c = t & 63, gr = t >> 6;
  float s = 0.f;
  for (int b = gr; b < nblk; b += 16) s += part[(long)b * 64 + c];
  sh[t] = s;
  __syncthreads();
  if (t < 64) {
    float tot = 0.f;
#pragma unroll
    for (int q = 0; q < 16; ++q) tot += sh[q * 64 + t];
    gmean[t] = tot * invN;
  }
  __syncthreads();
  if (t < 64) {
    float acc = out_b[t];
#pragma unroll
    for (int k = 0; k < 64; ++k) acc += gmean[k] * sW[k * 64 + t];
    out[t] = fmaxf(acc, 0.f);
  }
}

// ---------------- host launch ----------------
extern "C" void kernel_launch(void* const* d_in, const int* in_sizes, int n_in,
                              void* d_out, int out_size, void* d_ws, size_t ws_size,
                              hipStream_t stream) {
  const float* x        = (const float*)d_in[0];
  const int*   eidx     = (const int*)d_in[1];
  const float* eattr    = (const float*)d_in[2];
  const float* np_W1    = (const float*)d_in[3];
  const float* np_b1    = (const float*)d_in[4];
  const float* np_W2    = (const float*)d_in[5];
  const float* np_b2    = (const float*)d_in[6];
  const float* np_ln_g  = (const float*)d_in[7];
  const float* np_ln_b  = (const float*)d_in[8];
  const float* ep_W1    = (const float*)d_in[9];
  const float* ep_b1    = (const float*)d_in[10];
  const float* ep_W2    = (const float*)d_in[11];
  const float* ep_b2    = (const float*)d_in[12];
  const float* ep_ln_g  = (const float*)d_in[13];
  const float* ep_ln_b  = (const float*)d_in[14];
  const float* enc_W    = (const float*)d_in[15];
  const float* enc_b    = (const float*)d_in[16];
  const float* enc_bn_g = (const float*)d_in[17];
  const float* enc_bn_b = (const float*)d_in[18];
  const float* gat_W    = (const float*)d_in[19];
  const float* gat_eW   = (const float*)d_in[20];
  const float* att_src  = (const float*)d_in[21];
  const float* att_dst  = (const float*)d_in[22];
  const float* att_edge = (const float*)d_in[23];
  const float* gat_b    = (const float*)d_in[24];
  const float* bn_g     = (const float*)d_in[25];
  const float* bn_b     = (const float*)d_in[26];
  const float* out_W    = (const float*)d_in[27];
  const float* out_b    = (const float*)d_in[28];

  const int n = in_sizes[0] / 128;   // 50000
  const int ne = in_sizes[1] / 2;    // 800000
  const int* srcp = eidx;
  const int* dstp = eidx + ne;

  float* f = (float*)d_ws;
  float* hbuf  = f; f += (long)n * 64;
  float* zbuf  = f; f += (long)n * 64;   // also reused as eidt/rank scratch pre-node_pre3
  float* alsb  = f; f += n;
  float* aldb  = f; f += n;
  float* ale   = f; f += 3L * ne;
  float* vgbuf = f; f += 128;
  float* part  = f; f += 131072;      // 1024 x 128
  float* part2 = f; f += 16384;       // 256 x 64
  float* part3 = f; f += 4096;        // 32 x 128
  unsigned short* wbb   = (unsigned short*)f; f += 2048;          // edge weights
  unsigned short* wnb   = (unsigned short*)f; f += 36864;         // node weights
  unsigned short* wgatb = (unsigned short*)f; f += 6144;          // 3 x 4096 gat weights
  unsigned char*  xsb   = (unsigned char*)f;  f += (long)n * 16;  // n*64 fp8
  int* ip = (int*)f;
  int2* csr = (int2*)ip; ip += 2L * ne;
  int* degb = ip; ip += n;
  int* offb = ip; ip += n + 1;
  int* bsum = ip; ip += 256;
  int* eidt = (int*)zbuf;       // ne ints (3.2MB)
  int* rankb = eidt + ne;       // ne ints (3.2MB); zbuf 12.8MB total -- fits

  const int nbEdge = (ne + EB - 1) / EB;     // 6250
  const int nbNode = (n + 63) / 64;          // 782
  const int nbScan = (n + 255) / 256;        // 196
  const float invN = 1.f / n;

  hipMemsetAsync(degb, 0, (size_t)n * sizeof(int), stream);
  packall<<<338, 256, 0, stream>>>(gat_eW, att_edge, ep_ln_g, ep_ln_b, vgbuf,
                                   ep_W1, ep_W2, wbb, np_W1, np_W2, enc_W, wnb,
                                   gat_W, wgatb);
  deg_rank<<<1024, 256, 0, stream>>>(dstp, ne, degb, rankb);
  scan_blk<<<nbScan, 256, 0, stream>>>(degb, offb, bsum, n);
  scan_add2<<<nbScan, 256, 0, stream>>>(bsum, offb, n);
  scatter_lite<<<1024, 256, 0, stream>>>(dstp, rankb, ne, offb, eidt);
  csr_sort<<<1024, 256, 0, stream>>>(offb, eidt, srcp, csr, n);
  edge_pre4<<<nbEdge, 256, 0, stream>>>(eattr, wbb, ep_b1, ep_b2, vgbuf, ale, ne);
  node_pre3<<<nbNode, 256, 0, stream>>>(x, wnb, np_b1, np_b2, np_ln_g, np_ln_b,
                                        enc_b, zbuf, part, n);
  bn_red16<<<16, 256, 0, stream>>>(part, nbNode, part3);
  xs_bn2<<<nbNode, 256, 0, stream>>>(zbuf, part3, invN, enc_bn_g, enc_bn_b, hbuf, 0,
                                     wgatb, att_src, att_dst, xsb, alsb, aldb, n);
  for (int l = 0; l < 3; ++l) {
    gat5<<<1024, 256, 0, stream>>>(offb, csr, ale + (long)l * ne, alsb, aldb,
                                   xsb, gat_b + l * 64, zbuf, part, n);
    bn_red16<<<16, 256, 0, stream>>>(part, 1024, part3);
    if (l < 2) {
      xs_bn2<<<nbNode, 256, 0, stream>>>(zbuf, part3, invN, bn_g + l * 64, bn_b + l * 64,
                                         hbuf, 1, wgatb + (long)(l + 1) * 4096,
                                         att_src + (l + 1) * 64, att_dst + (l + 1) * 64,
                                         xsb, alsb, aldb, n);
    } else {
      gsum_bn<<<256, 256, 0, stream>>>(zbuf, part3, invN, bn_g + l * 64, bn_b + l * 64,
                                       hbuf, n, part2);
    }
  }
  final2<<<1, 1024, 0, stream>>>(part2, 256, out_W, out_b, (float*)d_out, invN);
}